// Round 3
// baseline (5942.057 us; speedup 1.0000x reference)
//
#include <hip/hip_runtime.h>
#include <hip/hip_bf16.h>

typedef __bf16 bf16x8 __attribute__((ext_vector_type(8)));
typedef float f32x4 __attribute__((ext_vector_type(4)));

#define HIDDEN 4096
#define NH 32
#define HD 128
#define SEQ 2048
#define BATCH 2
#define MTOT 4096           // BATCH*SEQ
#define QKV 12288

// Convert 8 contiguous bf16 (16B-aligned) to 8 floats.
__device__ __forceinline__ void b8f(const __hip_bfloat16* p, float* f) {
    uint4 raw = *(const uint4*)p;
    uint32_t w[4] = {raw.x, raw.y, raw.z, raw.w};
#pragma unroll
    for (int i = 0; i < 4; ++i) {
        f[2 * i]     = __uint_as_float(w[i] << 16);
        f[2 * i + 1] = __uint_as_float(w[i] & 0xffff0000u);
    }
}

// Load 8 source elements and return them as 8 packed bf16 (one uint4).
__device__ __forceinline__ uint4 ld8(const __hip_bfloat16* p) { return *(const uint4*)p; }
__device__ __forceinline__ uint4 ld8(const float* p) {
    float4 a = *(const float4*)p;
    float4 b = *(const float4*)(p + 4);
    __hip_bfloat16 t[8];
    t[0] = __float2bfloat16(a.x); t[1] = __float2bfloat16(a.y);
    t[2] = __float2bfloat16(a.z); t[3] = __float2bfloat16(a.w);
    t[4] = __float2bfloat16(b.x); t[5] = __float2bfloat16(b.y);
    t[6] = __float2bfloat16(b.z); t[7] = __float2bfloat16(b.w);
    return *(uint4*)t;
}

__device__ __forceinline__ void stc(__hip_bfloat16* C, size_t i, float v) { C[i] = __float2bfloat16(v); }
__device__ __forceinline__ void stc(float* C, size_t i, float v) { C[i] = v; }

// C[M,N] = A[M,K] @ Bt[N,K]^T. A/B any of {float,bf16} (converted to bf16 at LDS
// staging), fp32 MFMA accumulate, C stored as TC. 128x128 tile per block
// (256 thr / 4 waves), each wave 64x64 = 4x4 MFMA tiles, BK=32.
template <typename TA, typename TB, typename TC>
__global__ __launch_bounds__(256) void gemm_bt(const TA* __restrict__ A,
                                               const TB* __restrict__ Bt,
                                               TC* __restrict__ C,
                                               int M, int N, int K) {
    __shared__ __align__(16) __hip_bfloat16 As[128][32];
    __shared__ __align__(16) __hip_bfloat16 Bs[128][32];
    const int bn = blockIdx.x * 128, bm = blockIdx.y * 128;
    const int tid = threadIdx.x, wave = tid >> 6, lane = tid & 63;
    const int wm = (wave >> 1) * 64, wn = (wave & 1) * 64;
    const int row16 = lane & 15, quad = lane >> 4;
    const int arow = tid >> 2;          // 0..63
    const int acol = (tid & 3) * 8;     // 0,8,16,24

    f32x4 acc[4][4] = {};

    for (int kt = 0; kt < K; kt += 32) {
        __syncthreads();
#pragma unroll
        for (int it = 0; it < 2; ++it) {
            int r = arow + it * 64;
            *(uint4*)&As[r][acol] = ld8(&A[(size_t)(bm + r) * K + kt + acol]);
            *(uint4*)&Bs[r][acol] = ld8(&Bt[(size_t)(bn + r) * K + kt + acol]);
        }
        __syncthreads();
        bf16x8 af[4], bf[4];
#pragma unroll
        for (int i = 0; i < 4; ++i) af[i] = *(const bf16x8*)&As[wm + i * 16 + row16][quad * 8];
#pragma unroll
        for (int j = 0; j < 4; ++j) bf[j] = *(const bf16x8*)&Bs[wn + j * 16 + row16][quad * 8];
#pragma unroll
        for (int i = 0; i < 4; ++i)
#pragma unroll
            for (int j = 0; j < 4; ++j)
                acc[i][j] = __builtin_amdgcn_mfma_f32_16x16x32_bf16(af[i], bf[j], acc[i][j], 0, 0, 0);
    }
    // C/D layout: col = lane&15, row = quad*4 + reg  (m89/m91-verified)
    const int col0 = bn + wn + row16;
    const int row0 = bm + wm + quad * 4;
#pragma unroll
    for (int i = 0; i < 4; ++i)
#pragma unroll
        for (int j = 0; j < 4; ++j)
#pragma unroll
            for (int rg = 0; rg < 4; ++rg)
                stc(C, (size_t)(row0 + i * 16 + rg) * N + col0 + j * 16, acc[i][j][rg]);
}

// In-place RoPE on the Q and K thirds of proj[MTOT][QKV]. position = row % SEQ.
__global__ __launch_bounds__(256) void rope_kernel(__hip_bfloat16* __restrict__ proj) {
    int t = blockIdx.x * 256 + threadIdx.x;      // 4096 rows * 2 mats * 32 heads * 64 pairs
    int j = t & 63;
    int head = (t >> 6) & 31;
    int mat = (t >> 11) & 1;
    int row = t >> 12;
    int pos = row & (SEQ - 1);
    // inv_freq[j] = 10000^(-j/64) = exp(-j * ln(10000)/64)
    float invf = __expf(-(float)j * 0.14391156514261f);
    float ang = (float)pos * invf;
    // v_sin/v_cos have limited input domain -> explicit range reduction to [0,1) revolutions.
    float rev = ang * 0.15915494309189535f;
    rev -= floorf(rev);
    float arad = rev * 6.283185307179586f;   // [0, 2pi)
    float sn = __sinf(arad);
    float cs = __cosf(arad);
    size_t base = (size_t)row * QKV + mat * HIDDEN + head * HD + j;
    float x1 = __bfloat162float(proj[base]);
    float x2 = __bfloat162float(proj[base + 64]);
    proj[base]      = __float2bfloat16(x1 * cs - x2 * sn);
    proj[base + 64] = __float2bfloat16(x2 * cs + x1 * sn);
}

// Flash-style causal attention. Block = (q-tile of 64 rows) x (b,h). 4 waves; wave w owns
// q rows w*16..w*16+15. Keys processed in tiles of 64 staged in LDS. VALU fp32 compute.
__global__ __launch_bounds__(256) void attn_kernel(const __hip_bfloat16* __restrict__ proj,
                                                   __hip_bfloat16* __restrict__ out) {
    __shared__ __align__(16) __hip_bfloat16 Qs[64][128];
    __shared__ __align__(16) __hip_bfloat16 Ks[64][136];   // pad: stride 68 dw
    __shared__ __align__(16) __hip_bfloat16 Vt[128][72];   // transposed V, stride 36 dw
    __shared__ __align__(16) __hip_bfloat16 Ps[4][16][64];
    const int qt = blockIdx.x, bh = blockIdx.y;
    const int b = bh >> 5, h = bh & 31;
    const int q0 = qt << 6;
    const int tid = threadIdx.x, wave = tid >> 6, lane = tid & 63;
    const __hip_bfloat16* qb = proj + (size_t)b * SEQ * QKV + h * HD;
    const __hip_bfloat16* kb = qb + HIDDEN;
    const __hip_bfloat16* vb = qb + 2 * HIDDEN;

    for (int i = tid; i < 1024; i += 256) {
        int r = i >> 4, c = (i & 15) << 3;
        *(uint4*)&Qs[r][c] = *(const uint4*)&qb[(size_t)(q0 + r) * QKV + c];
    }

    float m_r[16], l_r[16], a0[16], a1[16], al[16];
#pragma unroll
    for (int r = 0; r < 16; ++r) { m_r[r] = -1e30f; l_r[r] = 0.f; a0[r] = 0.f; a1[r] = 0.f; }

    for (int kt = 0; kt <= qt; ++kt) {
        const int k0 = kt << 6;
        __syncthreads();
        for (int i = tid; i < 1024; i += 256) {
            int r = i >> 4, c = (i & 15) << 3;
            *(uint4*)&Ks[r][c] = *(const uint4*)&kb[(size_t)(k0 + r) * QKV + c];
            uint4 raw = *(const uint4*)&vb[(size_t)(k0 + r) * QKV + c];
            __hip_bfloat16 tmp[8];
            *(uint4*)tmp = raw;
#pragma unroll
            for (int x = 0; x < 8; ++x) Vt[c + x][r] = tmp[x];
        }
        __syncthreads();

        // ---- scores: lane j <-> key k0+j; 16 q-rows register-blocked ----
        float s[16];
#pragma unroll
        for (int r = 0; r < 16; ++r) s[r] = 0.f;
        for (int d = 0; d < 128; d += 8) {
            float kf[8];
            b8f(&Ks[lane][d], kf);
#pragma unroll
            for (int r = 0; r < 16; ++r) {
                float qf[8];
                b8f(&Qs[wave * 16 + r][d], qf);   // broadcast read
#pragma unroll
                for (int x = 0; x < 8; ++x) s[r] = fmaf(qf[x], kf[x], s[r]);
            }
        }
        const int key = k0 + lane;
#pragma unroll
        for (int r = 0; r < 16; ++r) {
            int q = q0 + wave * 16 + r;
            bool masked = key > q;
            float sv = masked ? -1e30f : s[r] * 0.08838834764831845f;   // 1/sqrt(128)
            float mt = sv;
#pragma unroll
            for (int off = 32; off > 0; off >>= 1) mt = fmaxf(mt, __shfl_xor(mt, off));
            float mn = fmaxf(m_r[r], mt);
            al[r] = __expf(m_r[r] - mn);
            m_r[r] = mn;
            float p = masked ? 0.0f : __expf(sv - mn);
            float ps = p;
#pragma unroll
            for (int off = 32; off > 0; off >>= 1) ps += __shfl_xor(ps, off);
            l_r[r] = l_r[r] * al[r] + ps;
            Ps[wave][r][lane] = __float2bfloat16(p);
        }
        // Fence between scalar-bf16 Ps writes and vector Ps reads (TBAA-distinct).
        __syncthreads();

        // ---- PV: lane d' <-> dims {d', d'+64} ----
#pragma unroll
        for (int r = 0; r < 16; ++r) { a0[r] *= al[r]; a1[r] *= al[r]; }
        for (int j8 = 0; j8 < 64; j8 += 8) {
            float va[8], vbv[8];
            b8f(&Vt[lane][j8], va);
            b8f(&Vt[lane + 64][j8], vbv);
#pragma unroll
            for (int r = 0; r < 16; ++r) {
                float pf[8];
                b8f(&Ps[wave][r][j8], pf);   // broadcast read
#pragma unroll
                for (int x = 0; x < 8; ++x) {
                    a0[r] = fmaf(pf[x], va[x], a0[r]);
                    a1[r] = fmaf(pf[x], vbv[x], a1[r]);
                }
            }
        }
    }
    // write attn_out in [B,S,H*D] layout so GEMM2 consumes it directly
    __hip_bfloat16* ob = out + (size_t)b * SEQ * HIDDEN + h * HD;
#pragma unroll
    for (int r = 0; r < 16; ++r) {
        float inv = l_r[r] > 0.f ? 1.0f / l_r[r] : 0.f;
        size_t row = (size_t)(q0 + wave * 16 + r) * HIDDEN;
        ob[row + lane]      = __float2bfloat16(a0[r] * inv);
        ob[row + lane + 64] = __float2bfloat16(a1[r] * inv);
    }
}

extern "C" void kernel_launch(void* const* d_in, const int* in_sizes, int n_in,
                              void* d_out, int out_size, void* d_ws, size_t ws_size,
                              hipStream_t stream) {
    // Reference dtypes: hidden_states/W_pack/W_o are float32; mask+positions unused
    // (mask is structurally causal, position_ids is arange).
    const float* hs = (const float*)d_in[0];
    const float* Wp = (const float*)d_in[3];
    const float* Wo = (const float*)d_in[4];
    __hip_bfloat16* proj = (__hip_bfloat16*)d_ws;                       // [4096][12288] bf16
    __hip_bfloat16* attn = proj + (size_t)MTOT * QKV;                   // [4096][4096] bf16
    float* out = (float*)d_out;                                         // [2,2048,4096] fp32

    gemm_bt<<<dim3(QKV / 128, MTOT / 128), dim3(256), 0, stream>>>(hs, Wp, proj, MTOT, QKV, HIDDEN);
    rope_kernel<<<dim3((MTOT * 2 * NH * 64) / 256), dim3(256), 0, stream>>>(proj);
    attn_kernel<<<dim3(SEQ / 64, BATCH * NH), dim3(256), 0, stream>>>(proj, attn);
    gemm_bt<<<dim3(HIDDEN / 128, MTOT / 128), dim3(256), 0, stream>>>(attn, Wo, out, MTOT, HIDDEN, HIDDEN);
}

// Round 4
// 1734.492 us; speedup vs baseline: 3.4258x; 3.4258x over previous
//
#include <hip/hip_runtime.h>
#include <hip/hip_bf16.h>

typedef __bf16 bf16x8 __attribute__((ext_vector_type(8)));
typedef float f32x4 __attribute__((ext_vector_type(4)));

#define HIDDEN 4096
#define NH 32
#define HD 128
#define SEQ 2048
#define BATCH 2
#define MTOT 4096           // BATCH*SEQ
#define QKV 12288

// Load 8 source elements and return them as 8 packed bf16 (one uint4).
__device__ __forceinline__ uint4 ld8(const __hip_bfloat16* p) { return *(const uint4*)p; }
__device__ __forceinline__ uint4 ld8(const float* p) {
    float4 a = *(const float4*)p;
    float4 b = *(const float4*)(p + 4);
    __hip_bfloat16 t[8];
    t[0] = __float2bfloat16(a.x); t[1] = __float2bfloat16(a.y);
    t[2] = __float2bfloat16(a.z); t[3] = __float2bfloat16(a.w);
    t[4] = __float2bfloat16(b.x); t[5] = __float2bfloat16(b.y);
    t[6] = __float2bfloat16(b.z); t[7] = __float2bfloat16(b.w);
    return *(uint4*)t;
}

__device__ __forceinline__ void stc(__hip_bfloat16* C, size_t i, float v) { C[i] = __float2bfloat16(v); }
__device__ __forceinline__ void stc(float* C, size_t i, float v) { C[i] = v; }

// C[M,N] = A[M,K] @ Bt[N,K]^T. A/B any of {float,bf16} (converted to bf16 at LDS
// staging), fp32 MFMA accumulate. A row stride = lda (>= K). 128x128 tile/block.
template <typename TA, typename TB, typename TC>
__global__ __launch_bounds__(256) void gemm_bt(const TA* __restrict__ A,
                                               const TB* __restrict__ Bt,
                                               TC* __restrict__ C,
                                               int M, int N, int K, int lda) {
    __shared__ __align__(16) __hip_bfloat16 As[128][32];
    __shared__ __align__(16) __hip_bfloat16 Bs[128][32];
    const int bn = blockIdx.x * 128, bm = blockIdx.y * 128;
    const int tid = threadIdx.x, wave = tid >> 6;
    const int lane = tid & 63;
    const int wm = (wave >> 1) * 64, wn = (wave & 1) * 64;
    const int row16 = lane & 15, quad = lane >> 4;
    const int arow = tid >> 2;          // 0..63
    const int acol = (tid & 3) * 8;     // 0,8,16,24

    f32x4 acc[4][4] = {};

    for (int kt = 0; kt < K; kt += 32) {
        __syncthreads();
#pragma unroll
        for (int it = 0; it < 2; ++it) {
            int r = arow + it * 64;
            *(uint4*)&As[r][acol] = ld8(&A[(size_t)(bm + r) * lda + kt + acol]);
            *(uint4*)&Bs[r][acol] = ld8(&Bt[(size_t)(bn + r) * K + kt + acol]);
        }
        __syncthreads();
        bf16x8 af[4], bf[4];
#pragma unroll
        for (int i = 0; i < 4; ++i) af[i] = *(const bf16x8*)&As[wm + i * 16 + row16][quad * 8];
#pragma unroll
        for (int j = 0; j < 4; ++j) bf[j] = *(const bf16x8*)&Bs[wn + j * 16 + row16][quad * 8];
#pragma unroll
        for (int i = 0; i < 4; ++i)
#pragma unroll
            for (int j = 0; j < 4; ++j)
                acc[i][j] = __builtin_amdgcn_mfma_f32_16x16x32_bf16(af[i], bf[j], acc[i][j], 0, 0, 0);
    }
    // C/D layout: col = lane&15, row = quad*4 + reg  (m89/m91-verified)
    const int col0 = bn + wn + row16;
    const int row0 = bm + wm + quad * 4;
#pragma unroll
    for (int i = 0; i < 4; ++i)
#pragma unroll
        for (int j = 0; j < 4; ++j)
#pragma unroll
            for (int rg = 0; rg < 4; ++rg)
                stc(C, (size_t)(row0 + i * 16 + rg) * N + col0 + j * 16, acc[i][j][rg]);
}

// In-place RoPE on the Q and K thirds of proj[MTOT][QKV]. position = row % SEQ.
__global__ __launch_bounds__(256) void rope_kernel(__hip_bfloat16* __restrict__ proj) {
    int t = blockIdx.x * 256 + threadIdx.x;
    int j = t & 63;
    int head = (t >> 6) & 31;
    int mat = (t >> 11) & 1;
    int row = t >> 12;
    int pos = row & (SEQ - 1);
    float invf = __expf(-(float)j * 0.14391156514261f);   // 10000^(-j/64)
    float ang = (float)pos * invf;
    float rev = ang * 0.15915494309189535f;               // range-reduce for v_sin/v_cos
    rev -= floorf(rev);
    float arad = rev * 6.283185307179586f;
    float sn = __sinf(arad);
    float cs = __cosf(arad);
    size_t base = (size_t)row * QKV + mat * HIDDEN + head * HD + j;
    float x1 = __bfloat162float(proj[base]);
    float x2 = __bfloat162float(proj[base + 64]);
    proj[base]      = __float2bfloat16(x1 * cs - x2 * sn);
    proj[base + 64] = __float2bfloat16(x2 * cs + x1 * sn);
}

// One-shot V transpose: proj V-third [b][s][h*128+d] -> vtg[(b*32+h)][d][s].
__global__ __launch_bounds__(256) void transpose_v(const __hip_bfloat16* __restrict__ proj,
                                                   __hip_bfloat16* __restrict__ vtg) {
    __shared__ __hip_bfloat16 Ls[64][132];   // stride 264B (8B-aligned); bank stride 66 dw
    const int st = blockIdx.x, bh = blockIdx.y;
    const int b = bh >> 5, h = bh & 31;
    const int s0 = st << 6;
    const int tid = threadIdx.x;
    const __hip_bfloat16* vb = proj + (size_t)b * SEQ * QKV + 2 * HIDDEN + h * HD;
    for (int i = tid; i < 1024; i += 256) {
        int r = i >> 4, c = (i & 15) << 3;
        uint4 raw = *(const uint4*)&vb[(size_t)(s0 + r) * QKV + c];
        *(uint2*)&Ls[r][c]     = make_uint2(raw.x, raw.y);
        *(uint2*)&Ls[r][c + 4] = make_uint2(raw.z, raw.w);
    }
    __syncthreads();
    __hip_bfloat16* ob = vtg + (size_t)bh * HD * SEQ + s0;
    for (int t = tid; t < 1024; t += 256) {
        int d = t >> 3, sc = (t & 7) << 3;
        __hip_bfloat16 tmp[8];
#pragma unroll
        for (int x = 0; x < 8; ++x) tmp[x] = Ls[sc + x][d];
        *(uint4*)&ob[(size_t)d * SEQ + sc] = *(uint4*)tmp;
    }
}

// MFMA flash attention. Block = 64 q-rows x (b,h); 4 waves x 16 q-rows each.
// K-tiles of 64 keys; K rows + pre-transposed V staged in LDS; P via LDS round-trip.
// O overwrites the Q-third of proj in place (block-unique region).
__global__ __launch_bounds__(256) void attn_mfma(__hip_bfloat16* __restrict__ proj,
                                                 const __hip_bfloat16* __restrict__ vtg) {
    __shared__ __align__(16) __hip_bfloat16 Ks[64][136];   // 17.4 KB
    __shared__ __align__(16) __hip_bfloat16 Vs[128][72];   // 18.4 KB (V^T tile)
    __shared__ __align__(16) __hip_bfloat16 Ps[4][16][72]; //  9.2 KB (wave-private P)
    const int qt = blockIdx.x, bh = blockIdx.y;
    const int b = bh >> 5, h = bh & 31;
    const int q0 = qt << 6;
    const int tid = threadIdx.x, wave = tid >> 6, lane = tid & 63;
    const int row16 = lane & 15, quad = lane >> 4;

    __hip_bfloat16* qb = proj + (size_t)b * SEQ * QKV + h * HD;   // Q third (also O dest)
    const __hip_bfloat16* kb = qb + HIDDEN;
    const __hip_bfloat16* vp = vtg + (size_t)bh * HD * SEQ;

    // Q A-fragments straight from global: A[m=row16][k=quad*8+j], 4 chunks of K=32.
    bf16x8 qf[4];
    {
        const __hip_bfloat16* qrow = qb + (size_t)(q0 + wave * 16 + row16) * QKV + quad * 8;
#pragma unroll
        for (int s = 0; s < 4; ++s) qf[s] = *(const bf16x8*)(qrow + s * 32);
    }

    f32x4 oa[8] = {};          // O accumulator, C layout, 8 d-tiles
    float m_i[4], l_i[4];
#pragma unroll
    for (int r = 0; r < 4; ++r) { m_i[r] = -3.0e38f; l_i[r] = 0.f; }

    for (int kt = 0; kt <= qt; ++kt) {
        const int k0 = kt << 6;
        __syncthreads();
        for (int i = tid; i < 1024; i += 256) {          // K: 64 keys x 128 d
            int r = i >> 4, c = (i & 15) << 3;
            *(uint4*)&Ks[r][c] = *(const uint4*)&kb[(size_t)(k0 + r) * QKV + c];
        }
        for (int i = tid; i < 1024; i += 256) {          // V^T: 128 d x 64 keys
            int d = i >> 3, ko = (i & 7) << 3;
            *(uint4*)&Vs[d][ko] = *(const uint4*)&vp[(size_t)d * SEQ + k0 + ko];
        }
        __syncthreads();

        // ---- QK^T: 4 key-tiles x 4 k-steps ----
        f32x4 sf[4] = {};
#pragma unroll
        for (int nt = 0; nt < 4; ++nt)
#pragma unroll
            for (int ks = 0; ks < 4; ++ks) {
                bf16x8 kf = *(const bf16x8*)&Ks[nt * 16 + row16][ks * 32 + quad * 8];
                sf[nt] = __builtin_amdgcn_mfma_f32_16x16x32_bf16(qf[ks], kf, sf[nt], 0, 0, 0);
            }
#pragma unroll
        for (int nt = 0; nt < 4; ++nt)
#pragma unroll
            for (int rg = 0; rg < 4; ++rg) sf[nt][rg] *= 0.08838834764831845f;
        if (kt == qt) {                                   // mask only on the diagonal tile
#pragma unroll
            for (int nt = 0; nt < 4; ++nt) {
                int key = k0 + nt * 16 + row16;
#pragma unroll
                for (int rg = 0; rg < 4; ++rg)
                    if (key > q0 + wave * 16 + quad * 4 + rg) sf[nt][rg] = -3.0e38f;
            }
        }
        // ---- online softmax (row rg lives in this quad's 16 lanes x 4 nt-regs) ----
        float alpha[4];
#pragma unroll
        for (int rg = 0; rg < 4; ++rg) {
            float mx = fmaxf(fmaxf(sf[0][rg], sf[1][rg]), fmaxf(sf[2][rg], sf[3][rg]));
#pragma unroll
            for (int off = 8; off > 0; off >>= 1) mx = fmaxf(mx, __shfl_xor(mx, off));
            float mn = fmaxf(m_i[rg], mx);
            alpha[rg] = __expf(m_i[rg] - mn);
            m_i[rg] = mn;
        }
        float rs[4] = {0.f, 0.f, 0.f, 0.f};
#pragma unroll
        for (int nt = 0; nt < 4; ++nt)
#pragma unroll
            for (int rg = 0; rg < 4; ++rg) {
                float p = __expf(sf[nt][rg] - m_i[rg]);
                rs[rg] += p;
                Ps[wave][quad * 4 + rg][nt * 16 + row16] = __float2bfloat16(p);
            }
#pragma unroll
        for (int rg = 0; rg < 4; ++rg) {
#pragma unroll
            for (int off = 8; off > 0; off >>= 1) rs[rg] += __shfl_xor(rs[rg], off);
            l_i[rg] = l_i[rg] * alpha[rg] + rs[rg];
        }
#pragma unroll
        for (int dt = 0; dt < 8; ++dt)
#pragma unroll
            for (int rg = 0; rg < 4; ++rg) oa[dt][rg] *= alpha[rg];
        __syncthreads();   // fences the scalar Ps writes vs the vector reads below

        // ---- PV: P (A layout from LDS) x V^T tiles ----
        bf16x8 pf0 = *(const bf16x8*)&Ps[wave][row16][quad * 8];
        bf16x8 pf1 = *(const bf16x8*)&Ps[wave][row16][32 + quad * 8];
#pragma unroll
        for (int dt = 0; dt < 8; ++dt) {
            bf16x8 v0 = *(const bf16x8*)&Vs[dt * 16 + row16][quad * 8];
            bf16x8 v1 = *(const bf16x8*)&Vs[dt * 16 + row16][32 + quad * 8];
            oa[dt] = __builtin_amdgcn_mfma_f32_16x16x32_bf16(pf0, v0, oa[dt], 0, 0, 0);
            oa[dt] = __builtin_amdgcn_mfma_f32_16x16x32_bf16(pf1, v1, oa[dt], 0, 0, 0);
        }
    }
    // epilogue: O (C layout) over the Q-third, in place
#pragma unroll
    for (int rg = 0; rg < 4; ++rg) {
        float inv = 1.0f / l_i[rg];
        __hip_bfloat16* orow = qb + (size_t)(q0 + wave * 16 + quad * 4 + rg) * QKV;
#pragma unroll
        for (int dt = 0; dt < 8; ++dt)
            orow[dt * 16 + row16] = __float2bfloat16(oa[dt][rg] * inv);
    }
}

extern "C" void kernel_launch(void* const* d_in, const int* in_sizes, int n_in,
                              void* d_out, int out_size, void* d_ws, size_t ws_size,
                              hipStream_t stream) {
    const float* hs = (const float*)d_in[0];
    const float* Wp = (const float*)d_in[3];
    const float* Wo = (const float*)d_in[4];
    __hip_bfloat16* proj = (__hip_bfloat16*)d_ws;                 // [4096][12288] bf16 (100.7 MB)
    __hip_bfloat16* vtg = proj + (size_t)MTOT * QKV;              // [64][128][2048] bf16 (33.6 MB)
    float* out = (float*)d_out;

    gemm_bt<<<dim3(QKV / 128, MTOT / 128), dim3(256), 0, stream>>>(hs, Wp, proj, MTOT, QKV, HIDDEN, HIDDEN);
    rope_kernel<<<dim3((MTOT * 2 * NH * 64) / 256), dim3(256), 0, stream>>>(proj);
    transpose_v<<<dim3(SEQ / 64, BATCH * NH), dim3(256), 0, stream>>>(proj, vtg);
    attn_mfma<<<dim3(SEQ / 64, BATCH * NH), dim3(256), 0, stream>>>(proj, vtg);
    // GEMM2 reads the in-place O region (Q-third of proj, row stride QKV)
    gemm_bt<<<dim3(HIDDEN / 128, MTOT / 128), dim3(256), 0, stream>>>(proj, Wo, out, MTOT, HIDDEN, HIDDEN, QKV);
}

// Round 5
// 1555.270 us; speedup vs baseline: 3.8206x; 1.1152x over previous
//
#include <hip/hip_runtime.h>
#include <hip/hip_bf16.h>

typedef __bf16 bf16x8 __attribute__((ext_vector_type(8)));
typedef float f32x4 __attribute__((ext_vector_type(4)));

#define HIDDEN 4096
#define NH 32
#define HD 128
#define SEQ 2048
#define BATCH 2
#define MTOT 4096           // BATCH*SEQ
#define QKV 12288

// ---- async global->LDS, 16B per lane; LDS dest = wave-uniform base + lane*16 ----
__device__ __forceinline__ void async16(const void* g, void* l) {
    __builtin_amdgcn_global_load_lds(
        (const __attribute__((address_space(1))) void*)(uintptr_t)g,
        (__attribute__((address_space(3))) void*)(uint32_t)(uintptr_t)l,
        16, 0, 0);
}

// Load 8 source elements and return them as 8 packed bf16 (one uint4).
__device__ __forceinline__ uint4 ld8(const __hip_bfloat16* p) { return *(const uint4*)p; }
__device__ __forceinline__ uint4 ld8(const float* p) {
    float4 a = *(const float4*)p;
    float4 b = *(const float4*)(p + 4);
    __hip_bfloat16 t[8];
    t[0] = __float2bfloat16(a.x); t[1] = __float2bfloat16(a.y);
    t[2] = __float2bfloat16(a.z); t[3] = __float2bfloat16(a.w);
    t[4] = __float2bfloat16(b.x); t[5] = __float2bfloat16(b.y);
    t[6] = __float2bfloat16(b.z); t[7] = __float2bfloat16(b.w);
    return *(uint4*)t;
}

__device__ __forceinline__ void stc(__hip_bfloat16* C, size_t i, float v) { C[i] = __float2bfloat16(v); }
__device__ __forceinline__ void stc(float* C, size_t i, float v) { C[i] = v; }

// fp32 -> bf16 bulk convert, 8 elems/thread.
__global__ __launch_bounds__(256) void cvt_bf16(const float* __restrict__ src,
                                                __hip_bfloat16* __restrict__ dst, int n8) {
    int i = blockIdx.x * 256 + threadIdx.x;
    if (i < n8) *(uint4*)&dst[(size_t)i * 8] = ld8(&src[(size_t)i * 8]);
}

// m97-style GEMM: C[M,N] = A[M,K] @ Bt[N,K]^T, bf16 in, fp32 MFMA acc.
// 128x128 tile, BK=32, staging via global_load_lds width=16 (2+2 insts/wave).
template <typename TC>
__global__ __launch_bounds__(256) void gemm_lds(const __hip_bfloat16* __restrict__ A,
                                                const __hip_bfloat16* __restrict__ Bt,
                                                TC* __restrict__ C,
                                                int M, int N, int K, int lda) {
    __shared__ __align__(16) __hip_bfloat16 As[128][32];
    __shared__ __align__(16) __hip_bfloat16 Bs[128][32];
    const int bn = blockIdx.x * 128, bm = blockIdx.y * 128;
    const int tid = threadIdx.x, wave = tid >> 6, lane = tid & 63;
    const int wm = (wave >> 1) * 64, wn = (wave & 1) * 64;
    const int row16 = lane & 15, quad = lane >> 4;
    const int lr = lane >> 2;          // 0..15: row within a 16-row chunk
    const int lc = (lane & 3) * 8;     // 0,8,16,24: col chunk
    // per-lane global addrs; LDS dests are wave-uniform (+lane*16 implicit)
    const __hip_bfloat16* Ab = A + (size_t)(bm + wave * 32 + lr) * lda + lc;
    const __hip_bfloat16* Bb = Bt + (size_t)(bn + wave * 32 + lr) * K + lc;

    f32x4 acc[4][4] = {};

    for (int kt = 0; kt < K; kt += 32) {
        __syncthreads();
        async16(Ab + kt,                   &As[wave * 32][0]);
        async16(Ab + (size_t)16 * lda + kt, &As[wave * 32 + 16][0]);
        async16(Bb + kt,                   &Bs[wave * 32][0]);
        async16(Bb + (size_t)16 * K + kt,  &Bs[wave * 32 + 16][0]);
        __syncthreads();
        bf16x8 af[4], bf[4];
#pragma unroll
        for (int i = 0; i < 4; ++i) af[i] = *(const bf16x8*)&As[wm + i * 16 + row16][quad * 8];
#pragma unroll
        for (int j = 0; j < 4; ++j) bf[j] = *(const bf16x8*)&Bs[wn + j * 16 + row16][quad * 8];
#pragma unroll
        for (int i = 0; i < 4; ++i)
#pragma unroll
            for (int j = 0; j < 4; ++j)
                acc[i][j] = __builtin_amdgcn_mfma_f32_16x16x32_bf16(af[i], bf[j], acc[i][j], 0, 0, 0);
    }
    const int col0 = bn + wn + row16;
    const int row0 = bm + wm + quad * 4;
#pragma unroll
    for (int i = 0; i < 4; ++i)
#pragma unroll
        for (int j = 0; j < 4; ++j)
#pragma unroll
            for (int rg = 0; rg < 4; ++rg)
                stc(C, (size_t)(row0 + i * 16 + rg) * N + col0 + j * 16, acc[i][j][rg]);
}

// Fallback GEMM (fp32 or bf16 inputs via ld8 staging). Used when ws is small.
template <typename TA, typename TB, typename TC>
__global__ __launch_bounds__(256) void gemm_bt(const TA* __restrict__ A,
                                               const TB* __restrict__ Bt,
                                               TC* __restrict__ C,
                                               int M, int N, int K, int lda) {
    __shared__ __align__(16) __hip_bfloat16 As[128][32];
    __shared__ __align__(16) __hip_bfloat16 Bs[128][32];
    const int bn = blockIdx.x * 128, bm = blockIdx.y * 128;
    const int tid = threadIdx.x, wave = tid >> 6, lane = tid & 63;
    const int wm = (wave >> 1) * 64, wn = (wave & 1) * 64;
    const int row16 = lane & 15, quad = lane >> 4;
    const int arow = tid >> 2;
    const int acol = (tid & 3) * 8;

    f32x4 acc[4][4] = {};

    for (int kt = 0; kt < K; kt += 32) {
        __syncthreads();
#pragma unroll
        for (int it = 0; it < 2; ++it) {
            int r = arow + it * 64;
            *(uint4*)&As[r][acol] = ld8(&A[(size_t)(bm + r) * lda + kt + acol]);
            *(uint4*)&Bs[r][acol] = ld8(&Bt[(size_t)(bn + r) * K + kt + acol]);
        }
        __syncthreads();
        bf16x8 af[4], bf[4];
#pragma unroll
        for (int i = 0; i < 4; ++i) af[i] = *(const bf16x8*)&As[wm + i * 16 + row16][quad * 8];
#pragma unroll
        for (int j = 0; j < 4; ++j) bf[j] = *(const bf16x8*)&Bs[wn + j * 16 + row16][quad * 8];
#pragma unroll
        for (int i = 0; i < 4; ++i)
#pragma unroll
            for (int j = 0; j < 4; ++j)
                acc[i][j] = __builtin_amdgcn_mfma_f32_16x16x32_bf16(af[i], bf[j], acc[i][j], 0, 0, 0);
    }
    const int col0 = bn + wn + row16;
    const int row0 = bm + wm + quad * 4;
#pragma unroll
    for (int i = 0; i < 4; ++i)
#pragma unroll
        for (int j = 0; j < 4; ++j)
#pragma unroll
            for (int rg = 0; rg < 4; ++rg)
                stc(C, (size_t)(row0 + i * 16 + rg) * N + col0 + j * 16, acc[i][j][rg]);
}

// In-place RoPE on the Q and K thirds of proj[MTOT][QKV]. position = row % SEQ.
__global__ __launch_bounds__(256) void rope_kernel(__hip_bfloat16* __restrict__ proj) {
    int t = blockIdx.x * 256 + threadIdx.x;
    int j = t & 63;
    int head = (t >> 6) & 31;
    int mat = (t >> 11) & 1;
    int row = t >> 12;
    int pos = row & (SEQ - 1);
    float invf = __expf(-(float)j * 0.14391156514261f);   // 10000^(-j/64)
    float ang = (float)pos * invf;
    float rev = ang * 0.15915494309189535f;               // range-reduce for v_sin/v_cos
    rev -= floorf(rev);
    float arad = rev * 6.283185307179586f;
    float sn = __sinf(arad);
    float cs = __cosf(arad);
    size_t base = (size_t)row * QKV + mat * HIDDEN + head * HD + j;
    float x1 = __bfloat162float(proj[base]);
    float x2 = __bfloat162float(proj[base + 64]);
    proj[base]      = __float2bfloat16(x1 * cs - x2 * sn);
    proj[base + 64] = __float2bfloat16(x2 * cs + x1 * sn);
}

// One-shot V transpose: proj V-third [b][s][h*128+d] -> vtg[(b*32+h)][d][s].
__global__ __launch_bounds__(256) void transpose_v(const __hip_bfloat16* __restrict__ proj,
                                                   __hip_bfloat16* __restrict__ vtg) {
    __shared__ __hip_bfloat16 Ls[64][132];
    const int st = blockIdx.x, bh = blockIdx.y;
    const int b = bh >> 5, h = bh & 31;
    const int s0 = st << 6;
    const int tid = threadIdx.x;
    const __hip_bfloat16* vb = proj + (size_t)b * SEQ * QKV + 2 * HIDDEN + h * HD;
    for (int i = tid; i < 1024; i += 256) {
        int r = i >> 4, c = (i & 15) << 3;
        uint4 raw = *(const uint4*)&vb[(size_t)(s0 + r) * QKV + c];
        *(uint2*)&Ls[r][c]     = make_uint2(raw.x, raw.y);
        *(uint2*)&Ls[r][c + 4] = make_uint2(raw.z, raw.w);
    }
    __syncthreads();
    __hip_bfloat16* ob = vtg + (size_t)bh * HD * SEQ + s0;
    for (int t = tid; t < 1024; t += 256) {
        int d = t >> 3, sc = (t & 7) << 3;
        __hip_bfloat16 tmp[8];
#pragma unroll
        for (int x = 0; x < 8; ++x) tmp[x] = Ls[sc + x][d];
        *(uint4*)&ob[(size_t)d * SEQ + sc] = *(uint4*)tmp;
    }
}

// MFMA flash attention. Block = 64 q-rows x (b,h); 4 waves x 16 q-rows each.
__global__ __launch_bounds__(256) void attn_mfma(__hip_bfloat16* __restrict__ proj,
                                                 const __hip_bfloat16* __restrict__ vtg) {
    __shared__ __align__(16) __hip_bfloat16 Ks[64][136];
    __shared__ __align__(16) __hip_bfloat16 Vs[128][72];
    __shared__ __align__(16) __hip_bfloat16 Ps[4][16][72];
    const int qt = blockIdx.x, bh = blockIdx.y;
    const int b = bh >> 5, h = bh & 31;
    const int q0 = qt << 6;
    const int tid = threadIdx.x, wave = tid >> 6, lane = tid & 63;
    const int row16 = lane & 15, quad = lane >> 4;

    __hip_bfloat16* qb = proj + (size_t)b * SEQ * QKV + h * HD;
    const __hip_bfloat16* kb = qb + HIDDEN;
    const __hip_bfloat16* vp = vtg + (size_t)bh * HD * SEQ;

    bf16x8 qf[4];
    {
        const __hip_bfloat16* qrow = qb + (size_t)(q0 + wave * 16 + row16) * QKV + quad * 8;
#pragma unroll
        for (int s = 0; s < 4; ++s) qf[s] = *(const bf16x8*)(qrow + s * 32);
    }

    f32x4 oa[8] = {};
    float m_i[4], l_i[4];
#pragma unroll
    for (int r = 0; r < 4; ++r) { m_i[r] = -3.0e38f; l_i[r] = 0.f; }

    for (int kt = 0; kt <= qt; ++kt) {
        const int k0 = kt << 6;
        __syncthreads();
        for (int i = tid; i < 1024; i += 256) {
            int r = i >> 4, c = (i & 15) << 3;
            *(uint4*)&Ks[r][c] = *(const uint4*)&kb[(size_t)(k0 + r) * QKV + c];
        }
        for (int i = tid; i < 1024; i += 256) {
            int d = i >> 3, ko = (i & 7) << 3;
            *(uint4*)&Vs[d][ko] = *(const uint4*)&vp[(size_t)d * SEQ + k0 + ko];
        }
        __syncthreads();

        f32x4 sf[4] = {};
#pragma unroll
        for (int nt = 0; nt < 4; ++nt)
#pragma unroll
            for (int ks = 0; ks < 4; ++ks) {
                bf16x8 kf = *(const bf16x8*)&Ks[nt * 16 + row16][ks * 32 + quad * 8];
                sf[nt] = __builtin_amdgcn_mfma_f32_16x16x32_bf16(qf[ks], kf, sf[nt], 0, 0, 0);
            }
#pragma unroll
        for (int nt = 0; nt < 4; ++nt)
#pragma unroll
            for (int rg = 0; rg < 4; ++rg) sf[nt][rg] *= 0.08838834764831845f;
        if (kt == qt) {
#pragma unroll
            for (int nt = 0; nt < 4; ++nt) {
                int key = k0 + nt * 16 + row16;
#pragma unroll
                for (int rg = 0; rg < 4; ++rg)
                    if (key > q0 + wave * 16 + quad * 4 + rg) sf[nt][rg] = -3.0e38f;
            }
        }
        float alpha[4];
#pragma unroll
        for (int rg = 0; rg < 4; ++rg) {
            float mx = fmaxf(fmaxf(sf[0][rg], sf[1][rg]), fmaxf(sf[2][rg], sf[3][rg]));
#pragma unroll
            for (int off = 8; off > 0; off >>= 1) mx = fmaxf(mx, __shfl_xor(mx, off));
            float mn = fmaxf(m_i[rg], mx);
            alpha[rg] = __expf(m_i[rg] - mn);
            m_i[rg] = mn;
        }
        float rs[4] = {0.f, 0.f, 0.f, 0.f};
#pragma unroll
        for (int nt = 0; nt < 4; ++nt)
#pragma unroll
            for (int rg = 0; rg < 4; ++rg) {
                float p = __expf(sf[nt][rg] - m_i[rg]);
                rs[rg] += p;
                Ps[wave][quad * 4 + rg][nt * 16 + row16] = __float2bfloat16(p);
            }
#pragma unroll
        for (int rg = 0; rg < 4; ++rg) {
#pragma unroll
            for (int off = 8; off > 0; off >>= 1) rs[rg] += __shfl_xor(rs[rg], off);
            l_i[rg] = l_i[rg] * alpha[rg] + rs[rg];
        }
#pragma unroll
        for (int dt = 0; dt < 8; ++dt)
#pragma unroll
            for (int rg = 0; rg < 4; ++rg) oa[dt][rg] *= alpha[rg];
        __syncthreads();

        bf16x8 pf0 = *(const bf16x8*)&Ps[wave][row16][quad * 8];
        bf16x8 pf1 = *(const bf16x8*)&Ps[wave][row16][32 + quad * 8];
#pragma unroll
        for (int dt = 0; dt < 8; ++dt) {
            bf16x8 v0 = *(const bf16x8*)&Vs[dt * 16 + row16][quad * 8];
            bf16x8 v1 = *(const bf16x8*)&Vs[dt * 16 + row16][32 + quad * 8];
            oa[dt] = __builtin_amdgcn_mfma_f32_16x16x32_bf16(pf0, v0, oa[dt], 0, 0, 0);
            oa[dt] = __builtin_amdgcn_mfma_f32_16x16x32_bf16(pf1, v1, oa[dt], 0, 0, 0);
        }
    }
#pragma unroll
    for (int rg = 0; rg < 4; ++rg) {
        float inv = 1.0f / l_i[rg];
        __hip_bfloat16* orow = qb + (size_t)(q0 + wave * 16 + quad * 4 + rg) * QKV;
#pragma unroll
        for (int dt = 0; dt < 8; ++dt)
            orow[dt * 16 + row16] = __float2bfloat16(oa[dt][rg] * inv);
    }
}

extern "C" void kernel_launch(void* const* d_in, const int* in_sizes, int n_in,
                              void* d_out, int out_size, void* d_ws, size_t ws_size,
                              hipStream_t stream) {
    const float* hs = (const float*)d_in[0];
    const float* Wp = (const float*)d_in[3];
    const float* Wo = (const float*)d_in[4];
    float* out = (float*)d_out;

    const size_t SZ_PROJ = (size_t)MTOT * QKV;      // bf16 elems
    const size_t SZ_H    = (size_t)MTOT * HIDDEN;
    const size_t SZ_WP   = (size_t)QKV * HIDDEN;
    const size_t need = (SZ_PROJ + SZ_H + SZ_WP + SZ_H) * sizeof(__hip_bfloat16);  // 256 MiB

    __hip_bfloat16* proj = (__hip_bfloat16*)d_ws;

    if (ws_size >= need) {
        // [proj][hsb][Wpb][Wob]; vtg aliases the (dead-after-GEMM1) hsb region.
        __hip_bfloat16* hsb = proj + SZ_PROJ;
        __hip_bfloat16* Wpb = hsb + SZ_H;
        __hip_bfloat16* Wob = Wpb + SZ_WP;
        __hip_bfloat16* vtg = hsb;   // 33.6 MB, fits in hsb+Wpb (134 MB)

        cvt_bf16<<<dim3(SZ_H / 8 / 256), dim3(256), 0, stream>>>(hs, hsb, SZ_H / 8);
        cvt_bf16<<<dim3(SZ_WP / 8 / 256), dim3(256), 0, stream>>>(Wp, Wpb, SZ_WP / 8);
        cvt_bf16<<<dim3(SZ_H / 8 / 256), dim3(256), 0, stream>>>(Wo, Wob, SZ_H / 8);
        gemm_lds<<<dim3(QKV / 128, MTOT / 128), dim3(256), 0, stream>>>(hsb, Wpb, proj, MTOT, QKV, HIDDEN, HIDDEN);
        rope_kernel<<<dim3((MTOT * 2 * NH * 64) / 256), dim3(256), 0, stream>>>(proj);
        transpose_v<<<dim3(SEQ / 64, BATCH * NH), dim3(256), 0, stream>>>(proj, vtg);
        attn_mfma<<<dim3(SEQ / 64, BATCH * NH), dim3(256), 0, stream>>>(proj, vtg);
        gemm_lds<<<dim3(HIDDEN / 128, MTOT / 128), dim3(256), 0, stream>>>(proj, Wob, out, MTOT, HIDDEN, HIDDEN, QKV);
    } else {
        // proven 128-MiB fallback (round-4 path)
        __hip_bfloat16* vtg = proj + SZ_PROJ;
        gemm_bt<<<dim3(QKV / 128, MTOT / 128), dim3(256), 0, stream>>>(hs, Wp, proj, MTOT, QKV, HIDDEN, HIDDEN);
        rope_kernel<<<dim3((MTOT * 2 * NH * 64) / 256), dim3(256), 0, stream>>>(proj);
        transpose_v<<<dim3(SEQ / 64, BATCH * NH), dim3(256), 0, stream>>>(proj, vtg);
        attn_mfma<<<dim3(SEQ / 64, BATCH * NH), dim3(256), 0, stream>>>(proj, vtg);
        gemm_bt<<<dim3(HIDDEN / 128, MTOT / 128), dim3(256), 0, stream>>>(proj, Wo, out, MTOT, HIDDEN, HIDDEN, QKV);
    }
}